// Round 1
// baseline (1269.917 us; speedup 1.0000x reference)
//
#include <hip/hip_runtime.h>
#include <hip/hip_bf16.h>

// Problem constants (from reference)
#define N_USERS    150000
#define N_ENTITIES 250000
#define CHN        64
#define N_RELM1    16      // N_REL - 1
#define N_FACTORS  4
#define N_EDGES    1000000
#define NNZ_       1000000
#define N_HOPS     2

// -------------------- small precompute: disen_weight + cor --------------------
__global__ void prep_small_kernel(const float* __restrict__ latent,   // unused here, kept for symmetry
                                  const float* __restrict__ weight,   // [16][64]
                                  const float* __restrict__ att,      // [4][16]
                                  float* __restrict__ disenw,         // [4][64] out
                                  float* __restrict__ cor_out)        // scalar out
{
    int tid = threadIdx.x;           // 256 threads: f = tid>>6, ch = tid&63
    int f  = tid >> 6;
    int ch = tid & 63;

    // softmax(att[f,:]) @ weight  -> disenw[f][ch]
    float m = -1e30f;
    for (int r = 0; r < N_RELM1; ++r) m = fmaxf(m, att[f * N_RELM1 + r]);
    float ex[N_RELM1];
    float s = 0.f;
    for (int r = 0; r < N_RELM1; ++r) { ex[r] = expf(att[f * N_RELM1 + r] - m); s += ex[r]; }
    float inv = 1.f / s;
    float acc = 0.f;
    for (int r = 0; r < N_RELM1; ++r) acc += (ex[r] * inv) * weight[r * CHN + ch];
    disenw[f * CHN + ch] = acc;

    if (tid == 0) {
        // cor = sum_{i<j} cos(att_i, att_j)^2
        float wn[N_FACTORS][N_RELM1];
        for (int i = 0; i < N_FACTORS; ++i) {
            float ss = 0.f;
            for (int r = 0; r < N_RELM1; ++r) { float v = att[i * N_RELM1 + r]; ss += v * v; }
            float innv = 1.f / sqrtf(ss);
            for (int r = 0; r < N_RELM1; ++r) wn[i][r] = att[i * N_RELM1 + r] * innv;
        }
        float cor = 0.f;
        for (int i = 0; i < N_FACTORS; ++i)
            for (int j = i + 1; j < N_FACTORS; ++j) {
                float d = 0.f;
                for (int r = 0; r < N_RELM1; ++r) d += wn[i][r] * wn[j][r];
                cor += d * d;
            }
        cor_out[0] = cor;
    }
}

// -------------------- init: copy embeddings into ws + d_out --------------------
__global__ __launch_bounds__(256) void init_copy_kernel(const float4* __restrict__ ent,
                                                        const float4* __restrict__ usr,
                                                        float4* __restrict__ e,
                                                        float4* __restrict__ u,
                                                        float4* __restrict__ out_ent,
                                                        float4* __restrict__ out_usr)
{
    const int n_ent4 = N_ENTITIES * (CHN / 4);
    const int n_usr4 = N_USERS * (CHN / 4);
    int i = blockIdx.x * blockDim.x + threadIdx.x;
    if (i < n_ent4) {
        float4 v = ent[i];
        e[i] = v;
        out_ent[i] = v;
    } else {
        int j = i - n_ent4;
        if (j < n_usr4) {
            float4 v = usr[j];
            u[j] = v;
            out_usr[j] = v;
        }
    }
}

// -------------------- head degree counts --------------------
__global__ __launch_bounds__(256) void count_heads_kernel(const int* __restrict__ head,
                                                          float* __restrict__ counts)
{
    int i = blockIdx.x * blockDim.x + threadIdx.x;
    if (i < N_EDGES) atomicAdd(&counts[head[i]], 1.0f);
}

// -------------------- KG edge scatter: agg[head] += e[tail]*weight[etype-1] ----
__global__ __launch_bounds__(256) void kg_scatter_kernel(const float* __restrict__ e,
                                                         const float* __restrict__ weight,
                                                         const int* __restrict__ head,
                                                         const int* __restrict__ tail,
                                                         const int* __restrict__ etype,
                                                         float* __restrict__ agg)
{
    unsigned int idx = blockIdx.x * blockDim.x + threadIdx.x;
    unsigned int edge = idx >> 6;
    int ch = idx & 63;
    if (edge >= N_EDGES) return;
    int t = tail[edge];
    int h = head[edge];
    int r = etype[edge] - 1;
    float v = e[(unsigned)t * CHN + ch] * weight[r * CHN + ch];
    atomicAdd(&agg[(unsigned)h * CHN + ch], v);
}

// -------------------- user scatter: uagg[row] += val * e[col] --------------------
__global__ __launch_bounds__(256) void user_scatter_kernel(const float* __restrict__ e,
                                                           const float* __restrict__ val,
                                                           const int* __restrict__ irow,
                                                           const int* __restrict__ icol,
                                                           float* __restrict__ uagg)
{
    unsigned int idx = blockIdx.x * blockDim.x + threadIdx.x;
    unsigned int nz = idx >> 6;
    int ch = idx & 63;
    if (nz >= NNZ_) return;
    int c = icol[nz];
    int rr = irow[nz];
    float v = val[nz] * e[(unsigned)c * CHN + ch];
    atomicAdd(&uagg[(unsigned)rr * CHN + ch], v);
}

// -------------------- entity update: e = l2norm(agg/denom); out += e ------------
__global__ __launch_bounds__(256) void entity_update_kernel(const float* __restrict__ agg,
                                                            const float* __restrict__ counts,
                                                            float* __restrict__ e,
                                                            float* __restrict__ out_ent)
{
    unsigned int idx = blockIdx.x * blockDim.x + threadIdx.x;
    unsigned int row = idx >> 6;
    int ch = idx & 63;
    if (row >= N_ENTITIES) return;
    float d = fmaxf(counts[row], 1.0f);
    float x = agg[row * CHN + ch] / d;
    float ss = x * x;
    #pragma unroll
    for (int off = 32; off > 0; off >>= 1) ss += __shfl_xor(ss, off, 64);
    float nrm = fmaxf(sqrtf(ss), 1e-12f);
    float y = x / nrm;
    e[row * CHN + ch] = y;
    out_ent[row * CHN + ch] += y;
}

// -------------------- user update -----------------------------------------------
// score = softmax(u_old @ latent^T); mix = sum_f score_f * disenw[f];
// x = uagg * (1 + mix); u = l2norm(x); out += u
__global__ __launch_bounds__(256) void user_update_kernel(const float* __restrict__ uagg,
                                                          float* __restrict__ u,
                                                          const float* __restrict__ latent,  // [4][64]
                                                          const float* __restrict__ disenw,  // [4][64]
                                                          float* __restrict__ out_usr)
{
    unsigned int idx = blockIdx.x * blockDim.x + threadIdx.x;
    unsigned int row = idx >> 6;
    int ch = idx & 63;
    if (row >= N_USERS) return;

    float uo = u[row * CHN + ch];

    // 4 dot products u_old . latent[f]
    float dot[N_FACTORS];
    #pragma unroll
    for (int f = 0; f < N_FACTORS; ++f) {
        float p = uo * latent[f * CHN + ch];
        #pragma unroll
        for (int off = 32; off > 0; off >>= 1) p += __shfl_xor(p, off, 64);
        dot[f] = p;
    }
    // softmax over 4 (every lane has full dot[])
    float m = fmaxf(fmaxf(dot[0], dot[1]), fmaxf(dot[2], dot[3]));
    float es = 0.f;
    #pragma unroll
    for (int f = 0; f < N_FACTORS; ++f) { dot[f] = expf(dot[f] - m); es += dot[f]; }
    float inv = 1.f / es;

    float mix = 0.f;
    #pragma unroll
    for (int f = 0; f < N_FACTORS; ++f) mix += (dot[f] * inv) * disenw[f * CHN + ch];

    float x = uagg[row * CHN + ch] * (1.f + mix);
    float ss = x * x;
    #pragma unroll
    for (int off = 32; off > 0; off >>= 1) ss += __shfl_xor(ss, off, 64);
    float nrm = fmaxf(sqrtf(ss), 1e-12f);
    float y = x / nrm;
    u[row * CHN + ch] = y;
    out_usr[row * CHN + ch] += y;
}

extern "C" void kernel_launch(void* const* d_in, const int* in_sizes, int n_in,
                              void* d_out, int out_size, void* d_ws, size_t ws_size,
                              hipStream_t stream) {
    const float* user_emb   = (const float*)d_in[0];
    const float* entity_emb = (const float*)d_in[1];
    const float* latent_emb = (const float*)d_in[2];
    const float* weight     = (const float*)d_in[3];
    const float* att        = (const float*)d_in[4];
    const float* inter_val  = (const float*)d_in[5];
    const int*   edge_index = (const int*)d_in[6];   // [2][N_EDGES]
    const int*   edge_type  = (const int*)d_in[7];
    const int*   inter_row  = (const int*)d_in[8];
    const int*   inter_col  = (const int*)d_in[9];

    const int* head = edge_index;
    const int* tail = edge_index + N_EDGES;

    float* out_ent = (float*)d_out;                              // [250000*64]
    float* out_usr = out_ent + (size_t)N_ENTITIES * CHN;         // [150000*64]
    float* out_cor = out_usr + (size_t)N_USERS * CHN;            // [1]

    // workspace layout (floats)
    float* e      = (float*)d_ws;                                // 16,000,000
    float* u      = e + (size_t)N_ENTITIES * CHN;                //  9,600,000
    float* eagg   = u + (size_t)N_USERS * CHN;                   // 16,000,000
    float* uagg   = eagg + (size_t)N_ENTITIES * CHN;             //  9,600,000
    float* counts = uagg + (size_t)N_USERS * CHN;                //    250,000
    float* disenw = counts + N_ENTITIES;                         //        256

    // degree counts
    hipMemsetAsync(counts, 0, N_ENTITIES * sizeof(float), stream);
    count_heads_kernel<<<(N_EDGES + 255) / 256, 256, 0, stream>>>(head, counts);

    // init e/u and residual outputs
    {
        int n4 = N_ENTITIES * (CHN / 4) + N_USERS * (CHN / 4);
        init_copy_kernel<<<(n4 + 255) / 256, 256, 0, stream>>>(
            (const float4*)entity_emb, (const float4*)user_emb,
            (float4*)e, (float4*)u, (float4*)out_ent, (float4*)out_usr);
    }

    // disen_weight + cor
    prep_small_kernel<<<1, 256, 0, stream>>>(latent_emb, weight, att, disenw, out_cor);

    const int scatter_blocks = (int)(((size_t)N_EDGES * CHN + 255) / 256);  // 250000
    const int ent_blocks = (N_ENTITIES * CHN) / 256;                        // 62500
    const int usr_blocks = (N_USERS * CHN) / 256;                           // 37500

    for (int hop = 0; hop < N_HOPS; ++hop) {
        // zero both agg buffers (contiguous)
        hipMemsetAsync(eagg, 0, (size_t)(N_ENTITIES + N_USERS) * CHN * sizeof(float), stream);

        kg_scatter_kernel<<<scatter_blocks, 256, 0, stream>>>(e, weight, head, tail, edge_type, eagg);
        user_scatter_kernel<<<scatter_blocks, 256, 0, stream>>>(e, inter_val, inter_row, inter_col, uagg);

        entity_update_kernel<<<ent_blocks, 256, 0, stream>>>(eagg, counts, e, out_ent);
        user_update_kernel<<<usr_blocks, 256, 0, stream>>>(uagg, u, latent_emb, disenw, out_usr);
    }
}

// Round 2
// 928.158 us; speedup vs baseline: 1.3682x; 1.3682x over previous
//
#include <hip/hip_runtime.h>
#include <hip/hip_bf16.h>

// Problem constants (from reference)
#define N_USERS    150000
#define N_ENTITIES 250000
#define CHN        64
#define N_RELM1    16      // N_REL - 1
#define N_FACTORS  4
#define N_EDGES    1000000
#define NNZ_       1000000
#define N_HOPS     2

// -------------------- small precompute: disen_weight + cor --------------------
__global__ void prep_small_kernel(const float* __restrict__ weight,   // [16][64]
                                  const float* __restrict__ att,      // [4][16]
                                  float* __restrict__ disenw,         // [4][64] out
                                  float* __restrict__ cor_out)        // scalar out
{
    int tid = threadIdx.x;           // 256 threads: f = tid>>6, ch = tid&63
    int f  = tid >> 6;
    int ch = tid & 63;

    // softmax(att[f,:]) @ weight  -> disenw[f][ch]
    float m = -1e30f;
    for (int r = 0; r < N_RELM1; ++r) m = fmaxf(m, att[f * N_RELM1 + r]);
    float ex[N_RELM1];
    float s = 0.f;
    for (int r = 0; r < N_RELM1; ++r) { ex[r] = expf(att[f * N_RELM1 + r] - m); s += ex[r]; }
    float inv = 1.f / s;
    float acc = 0.f;
    for (int r = 0; r < N_RELM1; ++r) acc += (ex[r] * inv) * weight[r * CHN + ch];
    disenw[f * CHN + ch] = acc;

    if (tid == 0) {
        float wn[N_FACTORS][N_RELM1];
        for (int i = 0; i < N_FACTORS; ++i) {
            float ss = 0.f;
            for (int r = 0; r < N_RELM1; ++r) { float v = att[i * N_RELM1 + r]; ss += v * v; }
            float innv = 1.f / sqrtf(ss);
            for (int r = 0; r < N_RELM1; ++r) wn[i][r] = att[i * N_RELM1 + r] * innv;
        }
        float cor = 0.f;
        for (int i = 0; i < N_FACTORS; ++i)
            for (int j = i + 1; j < N_FACTORS; ++j) {
                float d = 0.f;
                for (int r = 0; r < N_RELM1; ++r) d += wn[i][r] * wn[j][r];
                cor += d * d;
            }
        cor_out[0] = cor;
    }
}

// -------------------- counting sort: count --------------------
__global__ __launch_bounds__(256) void count_keys_kernel(const int* __restrict__ keys,
                                                         int* __restrict__ cnt, int n)
{
    int i = blockIdx.x * blockDim.x + threadIdx.x;
    if (i < n) atomicAdd(&cnt[keys[i]], 1);
}

// -------------------- counting sort: two-level exclusive scan --------------------
#define SCHUNK 512

__global__ __launch_bounds__(512) void block_sum_kernel(const int* __restrict__ cnt,
                                                        int* __restrict__ bsum, int n)
{
    __shared__ int sdata[SCHUNK];
    int t = threadIdx.x;
    int i = blockIdx.x * SCHUNK + t;
    sdata[t] = (i < n) ? cnt[i] : 0;
    __syncthreads();
    for (int off = SCHUNK / 2; off > 0; off >>= 1) {
        if (t < off) sdata[t] += sdata[t + off];
        __syncthreads();
    }
    if (t == 0) bsum[blockIdx.x] = sdata[0];
}

__global__ __launch_bounds__(512) void scan_small_kernel(int* __restrict__ bsum, int nb)
{
    // exclusive scan of up to 512 elements in-place (Hillis-Steele ping-pong)
    __shared__ int a[SCHUNK], b[SCHUNK];
    int t = threadIdx.x;
    a[t] = (t < nb) ? bsum[t] : 0;
    __syncthreads();
    int* src = a; int* dst = b;
    for (int off = 1; off < SCHUNK; off <<= 1) {
        dst[t] = src[t] + ((t >= off) ? src[t - off] : 0);
        __syncthreads();
        int* tm = src; src = dst; dst = tm;
    }
    int excl = (t == 0) ? 0 : src[t - 1];
    if (t < nb) bsum[t] = excl;
}

__global__ __launch_bounds__(512) void scan_chunk_kernel(const int* __restrict__ cnt,
                                                         const int* __restrict__ bsum,
                                                         int* __restrict__ offs,
                                                         int* __restrict__ cur, int n)
{
    __shared__ int a[SCHUNK], b[SCHUNK];
    int t = threadIdx.x;
    int i = blockIdx.x * SCHUNK + t;
    a[t] = (i < n) ? cnt[i] : 0;
    __syncthreads();
    int* src = a; int* dst = b;
    for (int off = 1; off < SCHUNK; off <<= 1) {
        dst[t] = src[t] + ((t >= off) ? src[t - off] : 0);
        __syncthreads();
        int* tm = src; src = dst; dst = tm;
    }
    int excl = ((t == 0) ? 0 : src[t - 1]) + bsum[blockIdx.x];
    if (i < n) { offs[i] = excl; cur[i] = excl; }
}

// -------------------- counting sort: slot scatter --------------------
__global__ __launch_bounds__(256) void scatter_edges_kernel(const int* __restrict__ head,
                                                            const int* __restrict__ tail,
                                                            const int* __restrict__ etype,
                                                            int* __restrict__ cur,
                                                            int2* __restrict__ sTR)
{
    int i = blockIdx.x * blockDim.x + threadIdx.x;
    if (i >= N_EDGES) return;
    int h = head[i];
    int slot = atomicAdd(&cur[h], 1);
    sTR[slot] = make_int2(tail[i], etype[i] - 1);
}

__global__ __launch_bounds__(256) void scatter_inter_kernel(const int* __restrict__ irow,
                                                            const int* __restrict__ icol,
                                                            const float* __restrict__ val,
                                                            int* __restrict__ cur,
                                                            int2* __restrict__ sCV)
{
    int i = blockIdx.x * blockDim.x + threadIdx.x;
    if (i >= NNZ_) return;
    int r = irow[i];
    int slot = atomicAdd(&cur[r], 1);
    sCV[slot] = make_int2(icol[i], __float_as_int(val[i]));
}

// -------------------- fused entity hop: pull-aggregate + mean + l2norm + residual ----
__global__ __launch_bounds__(256) void agg_entity_kernel(const float* __restrict__ e_old,
                                                         const int2* __restrict__ sTR,
                                                         const int* __restrict__ cnt,
                                                         const int* __restrict__ offs,
                                                         const float* __restrict__ weight,
                                                         const float* __restrict__ resid_src,
                                                         float* __restrict__ e_new,
                                                         float* __restrict__ out_ent)
{
    __shared__ float wl[N_RELM1 * CHN];
    int tid = threadIdx.x;
    #pragma unroll
    for (int k = tid; k < N_RELM1 * CHN; k += 256) wl[k] = weight[k];
    __syncthreads();

    unsigned idx = blockIdx.x * 256u + tid;
    unsigned row = idx >> 6;
    int ch = idx & 63;
    if (row >= N_ENTITIES) return;

    int n = cnt[row];
    int start = offs[row];
    float acc = 0.f;
    for (int k = 0; k < n; ++k) {
        int2 tr = sTR[start + k];
        acc += e_old[(size_t)tr.x * CHN + ch] * wl[tr.y * CHN + ch];
    }
    float d = (n > 0) ? (float)n : 1.f;   // scatter_mean denom = max(counts,1)
    float x = acc / d;
    float ss = x * x;
    #pragma unroll
    for (int off = 32; off > 0; off >>= 1) ss += __shfl_xor(ss, off, 64);
    float y = x / fmaxf(sqrtf(ss), 1e-12f);
    e_new[(size_t)row * CHN + ch] = y;
    out_ent[(size_t)row * CHN + ch] = resid_src[(size_t)row * CHN + ch] + y;
}

// -------------------- fused user hop: pull-aggregate + attention mix + l2norm + residual ----
__global__ __launch_bounds__(256) void agg_user_kernel(const float* __restrict__ e_old,
                                                       const int2* __restrict__ sCV,
                                                       const int* __restrict__ ucnt,
                                                       const int* __restrict__ uoffs,
                                                       const float* __restrict__ u_src,
                                                       const float* __restrict__ latent,  // [4][64]
                                                       const float* __restrict__ disenw,  // [4][64]
                                                       const float* __restrict__ resid_src,
                                                       float* __restrict__ u_out,
                                                       float* __restrict__ out_usr)
{
    unsigned idx = blockIdx.x * 256u + threadIdx.x;
    unsigned row = idx >> 6;
    int ch = idx & 63;
    if (row >= N_USERS) return;

    float uo = u_src[(size_t)row * CHN + ch];

    // score = softmax(u_old @ latent^T) over 4 factors
    float dot[N_FACTORS];
    #pragma unroll
    for (int f = 0; f < N_FACTORS; ++f) {
        float p = uo * latent[f * CHN + ch];
        #pragma unroll
        for (int off = 32; off > 0; off >>= 1) p += __shfl_xor(p, off, 64);
        dot[f] = p;
    }
    float m = fmaxf(fmaxf(dot[0], dot[1]), fmaxf(dot[2], dot[3]));
    float es = 0.f;
    #pragma unroll
    for (int f = 0; f < N_FACTORS; ++f) { dot[f] = expf(dot[f] - m); es += dot[f]; }
    float inv = 1.f / es;
    float mix = 0.f;
    #pragma unroll
    for (int f = 0; f < N_FACTORS; ++f) mix += (dot[f] * inv) * disenw[f * CHN + ch];

    // user_agg = sparse interact @ e_old
    int n = ucnt[row];
    int start = uoffs[row];
    float acc = 0.f;
    for (int k = 0; k < n; ++k) {
        int2 cv = sCV[start + k];
        acc += __int_as_float(cv.y) * e_old[(size_t)cv.x * CHN + ch];
    }
    float x = acc * (1.f + mix);
    float ss = x * x;
    #pragma unroll
    for (int off = 32; off > 0; off >>= 1) ss += __shfl_xor(ss, off, 64);
    float y = x / fmaxf(sqrtf(ss), 1e-12f);
    u_out[(size_t)row * CHN + ch] = y;
    out_usr[(size_t)row * CHN + ch] = resid_src[(size_t)row * CHN + ch] + y;
}

extern "C" void kernel_launch(void* const* d_in, const int* in_sizes, int n_in,
                              void* d_out, int out_size, void* d_ws, size_t ws_size,
                              hipStream_t stream) {
    const float* user_emb   = (const float*)d_in[0];
    const float* entity_emb = (const float*)d_in[1];
    const float* latent_emb = (const float*)d_in[2];
    const float* weight     = (const float*)d_in[3];
    const float* att        = (const float*)d_in[4];
    const float* inter_val  = (const float*)d_in[5];
    const int*   edge_index = (const int*)d_in[6];   // [2][N_EDGES]
    const int*   edge_type  = (const int*)d_in[7];
    const int*   inter_row  = (const int*)d_in[8];
    const int*   inter_col  = (const int*)d_in[9];

    const int* head = edge_index;
    const int* tail = edge_index + N_EDGES;

    float* out_ent = (float*)d_out;                              // [250000*64]
    float* out_usr = out_ent + (size_t)N_ENTITIES * CHN;         // [150000*64]
    float* out_cor = out_usr + (size_t)N_USERS * CHN;            // [1]

    // workspace layout
    float* eA     = (float*)d_ws;                                // 16,000,000 f
    float* eB     = eA + (size_t)N_ENTITIES * CHN;               // 16,000,000 f
    float* u      = eB + (size_t)N_ENTITIES * CHN;               //  9,600,000 f
    float* disenw = u + (size_t)N_USERS * CHN;                   //        256 f
    int*   sTR    = (int*)(disenw + 256);                        //  2,000,000 i (int2 x 1M)
    int*   sCV    = sTR + 2 * N_EDGES;                           //  2,000,000 i
    int*   cnt    = sCV + 2 * NNZ_;                              //    250,000 i
    int*   ucnt   = cnt + N_ENTITIES;                            //    150,000 i  (contiguous with cnt)
    int*   offs   = ucnt + N_USERS;                              //    250,000 i
    int*   uoffs  = offs + N_ENTITIES;                           //    150,000 i
    int*   cur    = uoffs + N_USERS;                             //    250,000 i
    int*   ucur   = cur + N_ENTITIES;                            //    150,000 i
    int*   bsE    = ucur + N_USERS;                              //        512 i
    int*   bsU    = bsE + SCHUNK;                                //        512 i

    const int edge_blocks = (N_EDGES + 255) / 256;               // 3907
    const int entE_blocks = (N_ENTITIES + SCHUNK - 1) / SCHUNK;  // 489
    const int entU_blocks = (N_USERS + SCHUNK - 1) / SCHUNK;     // 293

    // ---- build CSR for both graphs (per launch; deterministic structure) ----
    hipMemsetAsync(cnt, 0, (size_t)(N_ENTITIES + N_USERS) * sizeof(int), stream);
    count_keys_kernel<<<edge_blocks, 256, 0, stream>>>(head, cnt, N_EDGES);
    count_keys_kernel<<<edge_blocks, 256, 0, stream>>>(inter_row, ucnt, NNZ_);

    block_sum_kernel<<<entE_blocks, SCHUNK, 0, stream>>>(cnt, bsE, N_ENTITIES);
    block_sum_kernel<<<entU_blocks, SCHUNK, 0, stream>>>(ucnt, bsU, N_USERS);
    scan_small_kernel<<<1, SCHUNK, 0, stream>>>(bsE, entE_blocks);
    scan_small_kernel<<<1, SCHUNK, 0, stream>>>(bsU, entU_blocks);
    scan_chunk_kernel<<<entE_blocks, SCHUNK, 0, stream>>>(cnt, bsE, offs, cur, N_ENTITIES);
    scan_chunk_kernel<<<entU_blocks, SCHUNK, 0, stream>>>(ucnt, bsU, uoffs, ucur, N_USERS);

    scatter_edges_kernel<<<edge_blocks, 256, 0, stream>>>(head, tail, edge_type, cur, (int2*)sTR);
    scatter_inter_kernel<<<edge_blocks, 256, 0, stream>>>(inter_row, inter_col, inter_val, ucur, (int2*)sCV);

    prep_small_kernel<<<1, 256, 0, stream>>>(weight, att, disenw, out_cor);

    const int entA_blocks = (N_ENTITIES * CHN) / 256;            // 62500
    const int usrA_blocks = (N_USERS * CHN) / 256;               // 37500

    // ---- hop 1: read input embeddings directly; residual base = inputs ----
    agg_entity_kernel<<<entA_blocks, 256, 0, stream>>>(entity_emb, (const int2*)sTR, cnt, offs,
                                                       weight, entity_emb, eA, out_ent);
    agg_user_kernel<<<usrA_blocks, 256, 0, stream>>>(entity_emb, (const int2*)sCV, ucnt, uoffs,
                                                     user_emb, latent_emb, disenw,
                                                     user_emb, u, out_usr);

    // ---- hop 2: read eA/u; residual base = out (rmw) ----
    agg_entity_kernel<<<entA_blocks, 256, 0, stream>>>(eA, (const int2*)sTR, cnt, offs,
                                                       weight, out_ent, eB, out_ent);
    agg_user_kernel<<<usrA_blocks, 256, 0, stream>>>(eA, (const int2*)sCV, ucnt, uoffs,
                                                     u, latent_emb, disenw,
                                                     out_usr, u, out_usr);
}

// Round 3
// 711.078 us; speedup vs baseline: 1.7859x; 1.3053x over previous
//
#include <hip/hip_runtime.h>
#include <hip/hip_bf16.h>

// Problem constants (from reference)
#define N_USERS    150000
#define N_ENTITIES 250000
#define NROWS      (N_ENTITIES + N_USERS)   // unified CSR rows
#define CHN        64
#define N_RELM1    16      // N_REL - 1
#define N_FACTORS  4
#define N_EDGES    1000000
#define NNZ_       1000000
#define NRECS      (N_EDGES + NNZ_)

// -------------------- small precompute: disen_weight + cor --------------------
__global__ void prep_small_kernel(const float* __restrict__ weight,   // [16][64]
                                  const float* __restrict__ att,      // [4][16]
                                  float* __restrict__ disenw,         // [4][64] out
                                  float* __restrict__ cor_out)        // scalar out
{
    int tid = threadIdx.x;           // 256 threads: f = tid>>6, ch = tid&63
    int f  = tid >> 6;
    int ch = tid & 63;

    float m = -1e30f;
    for (int r = 0; r < N_RELM1; ++r) m = fmaxf(m, att[f * N_RELM1 + r]);
    float ex[N_RELM1];
    float s = 0.f;
    for (int r = 0; r < N_RELM1; ++r) { ex[r] = expf(att[f * N_RELM1 + r] - m); s += ex[r]; }
    float inv = 1.f / s;
    float acc = 0.f;
    for (int r = 0; r < N_RELM1; ++r) acc += (ex[r] * inv) * weight[r * CHN + ch];
    disenw[f * CHN + ch] = acc;

    if (tid == 0) {
        float wn[N_FACTORS][N_RELM1];
        for (int i = 0; i < N_FACTORS; ++i) {
            float ss = 0.f;
            for (int r = 0; r < N_RELM1; ++r) { float v = att[i * N_RELM1 + r]; ss += v * v; }
            float innv = 1.f / sqrtf(ss);
            for (int r = 0; r < N_RELM1; ++r) wn[i][r] = att[i * N_RELM1 + r] * innv;
        }
        float cor = 0.f;
        for (int i = 0; i < N_FACTORS; ++i)
            for (int j = i + 1; j < N_FACTORS; ++j) {
                float d = 0.f;
                for (int r = 0; r < N_RELM1; ++r) d += wn[i][r] * wn[j][r];
                cor += d * d;
            }
        cor_out[0] = cor;
    }
}

// -------------------- unified count --------------------
__global__ __launch_bounds__(256) void count_all_kernel(const int* __restrict__ head,
                                                        const int* __restrict__ irow,
                                                        int* __restrict__ cnt)
{
    int i = blockIdx.x * 256 + threadIdx.x;
    if (i < N_EDGES) {
        atomicAdd(&cnt[head[i]], 1);
    } else {
        int j = i - N_EDGES;
        if (j < NNZ_) atomicAdd(&cnt[N_ENTITIES + irow[j]], 1);
    }
}

// -------------------- two-level exclusive scan --------------------
#define SCHUNK 512

__global__ __launch_bounds__(SCHUNK) void block_sum_kernel(const int* __restrict__ cnt,
                                                           int* __restrict__ bsum, int n)
{
    __shared__ int sdata[SCHUNK];
    int t = threadIdx.x;
    int i = blockIdx.x * SCHUNK + t;
    sdata[t] = (i < n) ? cnt[i] : 0;
    __syncthreads();
    for (int off = SCHUNK / 2; off > 0; off >>= 1) {
        if (t < off) sdata[t] += sdata[t + off];
        __syncthreads();
    }
    if (t == 0) bsum[blockIdx.x] = sdata[0];
}

__global__ __launch_bounds__(1024) void scan_small_kernel(int* __restrict__ bsum, int nb)
{
    // exclusive scan of up to 1024 elements in-place (Hillis-Steele ping-pong)
    __shared__ int a[1024], b[1024];
    int t = threadIdx.x;
    a[t] = (t < nb) ? bsum[t] : 0;
    __syncthreads();
    int* src = a; int* dst = b;
    for (int off = 1; off < 1024; off <<= 1) {
        dst[t] = src[t] + ((t >= off) ? src[t - off] : 0);
        __syncthreads();
        int* tm = src; src = dst; dst = tm;
    }
    int excl = (t == 0) ? 0 : src[t - 1];
    if (t < nb) bsum[t] = excl;
}

__global__ __launch_bounds__(SCHUNK) void scan_chunk_kernel(const int* __restrict__ cnt,
                                                            const int* __restrict__ bsum,
                                                            int* __restrict__ offs,
                                                            int* __restrict__ cur, int n)
{
    __shared__ int a[SCHUNK], b[SCHUNK];
    int t = threadIdx.x;
    int i = blockIdx.x * SCHUNK + t;
    a[t] = (i < n) ? cnt[i] : 0;
    __syncthreads();
    int* src = a; int* dst = b;
    for (int off = 1; off < SCHUNK; off <<= 1) {
        dst[t] = src[t] + ((t >= off) ? src[t - off] : 0);
        __syncthreads();
        int* tm = src; src = dst; dst = tm;
    }
    int excl = ((t == 0) ? 0 : src[t - 1]) + bsum[blockIdx.x];
    if (i < n) { offs[i] = excl; cur[i] = excl; }
}

// -------------------- unified slot scatter --------------------
__global__ __launch_bounds__(256) void scatter_all_kernel(const int* __restrict__ head,
                                                          const int* __restrict__ tail,
                                                          const int* __restrict__ etype,
                                                          const int* __restrict__ irow,
                                                          const int* __restrict__ icol,
                                                          const float* __restrict__ val,
                                                          int* __restrict__ cur,
                                                          int2* __restrict__ recs)
{
    int i = blockIdx.x * 256 + threadIdx.x;
    if (i < N_EDGES) {
        int slot = atomicAdd(&cur[head[i]], 1);
        recs[slot] = make_int2(tail[i], etype[i] - 1);
    } else {
        int j = i - N_EDGES;
        if (j < NNZ_) {
            int slot = atomicAdd(&cur[N_ENTITIES + irow[j]], 1);
            recs[slot] = make_int2(icol[j], __float_as_int(val[j]));
        }
    }
}

// -------------------- fused hop: entity rows then user rows --------------------
// One wave per row (64 lanes = 64 channels). Record loads are batched 4-wide so
// the 4 gathers issue independently (breaks the load->load dependency chain).
__global__ __launch_bounds__(256) void hop_kernel(const float* __restrict__ e_old,
                                                  const float* __restrict__ u_src,
                                                  const int2* __restrict__ recs,
                                                  const int* __restrict__ cnt,
                                                  const int* __restrict__ offs,
                                                  const float* __restrict__ weight,  // [16][64]
                                                  const float* __restrict__ latent,  // [4][64]
                                                  const float* __restrict__ disenw,  // [4][64]
                                                  const float* __restrict__ ent_resid,
                                                  const float* __restrict__ usr_resid,
                                                  float* __restrict__ e_new,   // nullptr: skip store
                                                  float* __restrict__ u_new,   // nullptr: skip store
                                                  float* __restrict__ out_ent,
                                                  float* __restrict__ out_usr)
{
    __shared__ float wl[N_RELM1 * CHN];
    for (int k = threadIdx.x; k < N_RELM1 * CHN; k += 256) wl[k] = weight[k];
    __syncthreads();

    unsigned idx = blockIdx.x * 256u + threadIdx.x;
    unsigned row = idx >> 6;
    int ch = idx & 63;
    if (row >= NROWS) return;

    int n = cnt[row];
    int start = offs[row];

    if (row < N_ENTITIES) {
        // ---- entity aggregation: mean_k e_old[tail_k] * w[rel_k] ----
        float acc = 0.f;
        int k = 0;
        for (; k + 4 <= n; k += 4) {
            int2 t0 = recs[start + k];
            int2 t1 = recs[start + k + 1];
            int2 t2 = recs[start + k + 2];
            int2 t3 = recs[start + k + 3];
            float g0 = e_old[(size_t)t0.x * CHN + ch] * wl[t0.y * CHN + ch];
            float g1 = e_old[(size_t)t1.x * CHN + ch] * wl[t1.y * CHN + ch];
            float g2 = e_old[(size_t)t2.x * CHN + ch] * wl[t2.y * CHN + ch];
            float g3 = e_old[(size_t)t3.x * CHN + ch] * wl[t3.y * CHN + ch];
            acc += (g0 + g1) + (g2 + g3);
        }
        int rem = n - k;
        if (rem > 0) {
            int2 t0 = recs[start + k];
            int2 t1 = (rem > 1) ? recs[start + k + 1] : t0;
            int2 t2 = (rem > 2) ? recs[start + k + 2] : t0;
            float g0 = e_old[(size_t)t0.x * CHN + ch] * wl[t0.y * CHN + ch];
            float g1 = (rem > 1) ? e_old[(size_t)t1.x * CHN + ch] * wl[t1.y * CHN + ch] : 0.f;
            float g2 = (rem > 2) ? e_old[(size_t)t2.x * CHN + ch] * wl[t2.y * CHN + ch] : 0.f;
            acc += g0 + g1 + g2;
        }
        float d = (n > 0) ? (float)n : 1.f;
        float x = acc / d;
        float ss = x * x;
        #pragma unroll
        for (int off = 32; off > 0; off >>= 1) ss += __shfl_xor(ss, off, 64);
        float y = x / fmaxf(sqrtf(ss), 1e-12f);
        if (e_new) e_new[(size_t)row * CHN + ch] = y;
        out_ent[(size_t)row * CHN + ch] = ent_resid[(size_t)row * CHN + ch] + y;
    } else {
        unsigned ur = row - N_ENTITIES;
        // ---- user attention mix ----
        float uo = u_src[(size_t)ur * CHN + ch];
        float dot[N_FACTORS];
        #pragma unroll
        for (int f = 0; f < N_FACTORS; ++f) {
            float p = uo * latent[f * CHN + ch];
            #pragma unroll
            for (int off = 32; off > 0; off >>= 1) p += __shfl_xor(p, off, 64);
            dot[f] = p;
        }
        float m = fmaxf(fmaxf(dot[0], dot[1]), fmaxf(dot[2], dot[3]));
        float es = 0.f;
        #pragma unroll
        for (int f = 0; f < N_FACTORS; ++f) { dot[f] = expf(dot[f] - m); es += dot[f]; }
        float sinv = 1.f / es;
        float mix = 0.f;
        #pragma unroll
        for (int f = 0; f < N_FACTORS; ++f) mix += (dot[f] * sinv) * disenw[f * CHN + ch];

        // ---- user aggregation: sum_k val_k * e_old[col_k] ----
        float acc = 0.f;
        int k = 0;
        for (; k + 4 <= n; k += 4) {
            int2 t0 = recs[start + k];
            int2 t1 = recs[start + k + 1];
            int2 t2 = recs[start + k + 2];
            int2 t3 = recs[start + k + 3];
            float g0 = __int_as_float(t0.y) * e_old[(size_t)t0.x * CHN + ch];
            float g1 = __int_as_float(t1.y) * e_old[(size_t)t1.x * CHN + ch];
            float g2 = __int_as_float(t2.y) * e_old[(size_t)t2.x * CHN + ch];
            float g3 = __int_as_float(t3.y) * e_old[(size_t)t3.x * CHN + ch];
            acc += (g0 + g1) + (g2 + g3);
        }
        int rem = n - k;
        if (rem > 0) {
            int2 t0 = recs[start + k];
            int2 t1 = (rem > 1) ? recs[start + k + 1] : t0;
            int2 t2 = (rem > 2) ? recs[start + k + 2] : t0;
            float g0 = __int_as_float(t0.y) * e_old[(size_t)t0.x * CHN + ch];
            float g1 = (rem > 1) ? __int_as_float(t1.y) * e_old[(size_t)t1.x * CHN + ch] : 0.f;
            float g2 = (rem > 2) ? __int_as_float(t2.y) * e_old[(size_t)t2.x * CHN + ch] : 0.f;
            acc += g0 + g1 + g2;
        }
        float x = acc * (1.f + mix);
        float ss = x * x;
        #pragma unroll
        for (int off = 32; off > 0; off >>= 1) ss += __shfl_xor(ss, off, 64);
        float y = x / fmaxf(sqrtf(ss), 1e-12f);
        if (u_new) u_new[(size_t)ur * CHN + ch] = y;
        out_usr[(size_t)ur * CHN + ch] = usr_resid[(size_t)ur * CHN + ch] + y;
    }
}

extern "C" void kernel_launch(void* const* d_in, const int* in_sizes, int n_in,
                              void* d_out, int out_size, void* d_ws, size_t ws_size,
                              hipStream_t stream) {
    const float* user_emb   = (const float*)d_in[0];
    const float* entity_emb = (const float*)d_in[1];
    const float* latent_emb = (const float*)d_in[2];
    const float* weight     = (const float*)d_in[3];
    const float* att        = (const float*)d_in[4];
    const float* inter_val  = (const float*)d_in[5];
    const int*   edge_index = (const int*)d_in[6];   // [2][N_EDGES]
    const int*   edge_type  = (const int*)d_in[7];
    const int*   inter_row  = (const int*)d_in[8];
    const int*   inter_col  = (const int*)d_in[9];

    const int* head = edge_index;
    const int* tail = edge_index + N_EDGES;

    float* out_ent = (float*)d_out;                              // [250000*64]
    float* out_usr = out_ent + (size_t)N_ENTITIES * CHN;         // [150000*64]
    float* out_cor = out_usr + (size_t)N_USERS * CHN;            // [1]

    // workspace layout
    float* eA     = (float*)d_ws;                                // 16,000,000 f
    float* u      = eA + (size_t)N_ENTITIES * CHN;               //  9,600,000 f
    float* disenw = u + (size_t)N_USERS * CHN;                   //        256 f
    int*   recs   = (int*)(disenw + 256);                        //  4,000,000 i (int2 x 2M)
    int*   cnt    = recs + 2 * NRECS;                            //    400,000 i
    int*   offs   = cnt + NROWS;                                 //    400,000 i
    int*   cur    = offs + NROWS;                                //    400,000 i
    int*   bs     = cur + NROWS;                                 //      1,024 i

    const int rec_blocks  = (NRECS + 255) / 256;                 // 7813
    const int scan_blocks = (NROWS + SCHUNK - 1) / SCHUNK;       // 782

    // ---- build unified CSR (entities rows [0,250k), users rows [250k,400k)) ----
    hipMemsetAsync(cnt, 0, (size_t)NROWS * sizeof(int), stream);
    count_all_kernel<<<rec_blocks, 256, 0, stream>>>(head, inter_row, cnt);
    block_sum_kernel<<<scan_blocks, SCHUNK, 0, stream>>>(cnt, bs, NROWS);
    scan_small_kernel<<<1, 1024, 0, stream>>>(bs, scan_blocks);
    scan_chunk_kernel<<<scan_blocks, SCHUNK, 0, stream>>>(cnt, bs, offs, cur, NROWS);
    scatter_all_kernel<<<rec_blocks, 256, 0, stream>>>(head, tail, edge_type,
                                                       inter_row, inter_col, inter_val,
                                                       cur, (int2*)recs);

    prep_small_kernel<<<1, 256, 0, stream>>>(weight, att, disenw, out_cor);

    const int hop_blocks = (NROWS * CHN) / 256;                  // 100000

    // ---- hop 1: read input embeddings; residual base = inputs ----
    hop_kernel<<<hop_blocks, 256, 0, stream>>>(entity_emb, user_emb, (const int2*)recs,
                                               cnt, offs, weight, latent_emb, disenw,
                                               entity_emb, user_emb,
                                               eA, u, out_ent, out_usr);

    // ---- hop 2: read eA/u; residual base = out (in-place add); no e_new/u_new ----
    hop_kernel<<<hop_blocks, 256, 0, stream>>>(eA, u, (const int2*)recs,
                                               cnt, offs, weight, latent_emb, disenw,
                                               out_ent, out_usr,
                                               nullptr, nullptr, out_ent, out_usr);
}

// Round 4
// 452.451 us; speedup vs baseline: 2.8067x; 1.5716x over previous
//
#include <hip/hip_runtime.h>
#include <hip/hip_bf16.h>

// Problem constants (from reference)
#define N_USERS    150000
#define N_ENTITIES 250000
#define NROWS      (N_ENTITIES + N_USERS)   // unified CSR rows
#define CHN        64
#define N_RELM1    16      // N_REL - 1
#define N_FACTORS  4
#define N_EDGES    1000000
#define NNZ_       1000000
#define NRECS      (N_EDGES + NNZ_)

__device__ __forceinline__ unsigned short f2bf(float f) {
    unsigned u = __float_as_uint(f);
    return (unsigned short)((u + 0x7fffu + ((u >> 16) & 1u)) >> 16);  // RNE
}
__device__ __forceinline__ float bf2f(unsigned short h) {
    return __uint_as_float(((unsigned)h) << 16);
}
__device__ __forceinline__ float4 bf4_to_f4(ushort4 v) {
    return make_float4(bf2f(v.x), bf2f(v.y), bf2f(v.z), bf2f(v.w));
}

// -------------------- small precompute: disen_weight + cor --------------------
__global__ void prep_small_kernel(const float* __restrict__ weight,   // [16][64]
                                  const float* __restrict__ att,      // [4][16]
                                  float* __restrict__ disenw,         // [4][64] out
                                  float* __restrict__ cor_out)        // scalar out
{
    int tid = threadIdx.x;           // 256 threads: f = tid>>6, ch = tid&63
    int f  = tid >> 6;
    int ch = tid & 63;

    float m = -1e30f;
    for (int r = 0; r < N_RELM1; ++r) m = fmaxf(m, att[f * N_RELM1 + r]);
    float ex[N_RELM1];
    float s = 0.f;
    for (int r = 0; r < N_RELM1; ++r) { ex[r] = expf(att[f * N_RELM1 + r] - m); s += ex[r]; }
    float inv = 1.f / s;
    float acc = 0.f;
    for (int r = 0; r < N_RELM1; ++r) acc += (ex[r] * inv) * weight[r * CHN + ch];
    disenw[f * CHN + ch] = acc;

    if (tid == 0) {
        float wn[N_FACTORS][N_RELM1];
        for (int i = 0; i < N_FACTORS; ++i) {
            float ss = 0.f;
            for (int r = 0; r < N_RELM1; ++r) { float v = att[i * N_RELM1 + r]; ss += v * v; }
            float innv = 1.f / sqrtf(ss);
            for (int r = 0; r < N_RELM1; ++r) wn[i][r] = att[i * N_RELM1 + r] * innv;
        }
        float cor = 0.f;
        for (int i = 0; i < N_FACTORS; ++i)
            for (int j = i + 1; j < N_FACTORS; ++j) {
                float d = 0.f;
                for (int r = 0; r < N_RELM1; ++r) d += wn[i][r] * wn[j][r];
                cor += d * d;
            }
        cor_out[0] = cor;
    }
}

// -------------------- f32 -> bf16 table conversion --------------------
__global__ __launch_bounds__(256) void conv_bf16_kernel(const float4* __restrict__ src,
                                                        ushort4* __restrict__ dst, int n4)
{
    int i = blockIdx.x * 256 + threadIdx.x;
    if (i >= n4) return;
    float4 v = src[i];
    dst[i] = make_ushort4(f2bf(v.x), f2bf(v.y), f2bf(v.z), f2bf(v.w));
}

// -------------------- unified count --------------------
__global__ __launch_bounds__(256) void count_all_kernel(const int* __restrict__ head,
                                                        const int* __restrict__ irow,
                                                        int* __restrict__ cnt)
{
    int i = blockIdx.x * 256 + threadIdx.x;
    if (i < N_EDGES) {
        atomicAdd(&cnt[head[i]], 1);
    } else {
        int j = i - N_EDGES;
        if (j < NNZ_) atomicAdd(&cnt[N_ENTITIES + irow[j]], 1);
    }
}

// -------------------- two-level exclusive scan --------------------
#define SCHUNK 512

__global__ __launch_bounds__(SCHUNK) void block_sum_kernel(const int* __restrict__ cnt,
                                                           int* __restrict__ bsum, int n)
{
    __shared__ int sdata[SCHUNK];
    int t = threadIdx.x;
    int i = blockIdx.x * SCHUNK + t;
    sdata[t] = (i < n) ? cnt[i] : 0;
    __syncthreads();
    for (int off = SCHUNK / 2; off > 0; off >>= 1) {
        if (t < off) sdata[t] += sdata[t + off];
        __syncthreads();
    }
    if (t == 0) bsum[blockIdx.x] = sdata[0];
}

__global__ __launch_bounds__(1024) void scan_small_kernel(int* __restrict__ bsum, int nb)
{
    __shared__ int a[1024], b[1024];
    int t = threadIdx.x;
    a[t] = (t < nb) ? bsum[t] : 0;
    __syncthreads();
    int* src = a; int* dst = b;
    for (int off = 1; off < 1024; off <<= 1) {
        dst[t] = src[t] + ((t >= off) ? src[t - off] : 0);
        __syncthreads();
        int* tm = src; src = dst; dst = tm;
    }
    int excl = (t == 0) ? 0 : src[t - 1];
    if (t < nb) bsum[t] = excl;
}

__global__ __launch_bounds__(SCHUNK) void scan_chunk_kernel(const int* __restrict__ cnt,
                                                            const int* __restrict__ bsum,
                                                            int* __restrict__ offs,
                                                            int* __restrict__ cur, int n)
{
    __shared__ int a[SCHUNK], b[SCHUNK];
    int t = threadIdx.x;
    int i = blockIdx.x * SCHUNK + t;
    a[t] = (i < n) ? cnt[i] : 0;
    __syncthreads();
    int* src = a; int* dst = b;
    for (int off = 1; off < SCHUNK; off <<= 1) {
        dst[t] = src[t] + ((t >= off) ? src[t - off] : 0);
        __syncthreads();
        int* tm = src; src = dst; dst = tm;
    }
    int excl = ((t == 0) ? 0 : src[t - 1]) + bsum[blockIdx.x];
    if (i < n) { offs[i] = excl; cur[i] = excl; }
}

// -------------------- unified slot scatter --------------------
__global__ __launch_bounds__(256) void scatter_all_kernel(const int* __restrict__ head,
                                                          const int* __restrict__ tail,
                                                          const int* __restrict__ etype,
                                                          const int* __restrict__ irow,
                                                          const int* __restrict__ icol,
                                                          const float* __restrict__ val,
                                                          int* __restrict__ cur,
                                                          int2* __restrict__ recs)
{
    int i = blockIdx.x * 256 + threadIdx.x;
    if (i < N_EDGES) {
        int slot = atomicAdd(&cur[head[i]], 1);
        recs[slot] = make_int2(tail[i], etype[i] - 1);
    } else {
        int j = i - N_EDGES;
        if (j < NNZ_) {
            int slot = atomicAdd(&cur[N_ENTITIES + irow[j]], 1);
            recs[slot] = make_int2(icol[j], __float_as_int(val[j]));
        }
    }
}

// -------------------- fused hop: 16 lanes per row, float4 per lane ------------
// Gather table is bf16 (half the random-gather bytes). A wave covers 4 rows ->
// 4 independent record streams x unroll-4 = up to 16 gathers in flight.
__global__ __launch_bounds__(256) void hop_kernel(const unsigned short* __restrict__ ebf,  // [N_ENTITIES][64] bf16
                                                  const float* __restrict__ u_src,
                                                  const int2* __restrict__ recs,
                                                  const int* __restrict__ cnt,
                                                  const int* __restrict__ offs,
                                                  const float* __restrict__ weight,  // [16][64] f32
                                                  const float* __restrict__ latent,  // [4][64]
                                                  const float* __restrict__ disenw,  // [4][64]
                                                  const float* __restrict__ ent_resid,
                                                  const float* __restrict__ usr_resid,
                                                  unsigned short* __restrict__ ebf_new,  // nullptr: skip
                                                  float* __restrict__ u_new,             // nullptr: skip
                                                  float* __restrict__ out_ent,
                                                  float* __restrict__ out_usr)
{
    __shared__ float wl[N_RELM1 * CHN];
    for (int k = threadIdx.x; k < N_RELM1 * CHN; k += 256) wl[k] = weight[k];
    __syncthreads();

    unsigned idx = blockIdx.x * 256u + threadIdx.x;
    unsigned row = idx >> 4;          // 16 lanes per row
    int cg = idx & 15;                // channel group: floats [cg*4, cg*4+4)
    if (row >= NROWS) return;

    int n = cnt[row];
    int start = offs[row];

    if (row < N_ENTITIES) {
        float4 acc = make_float4(0.f, 0.f, 0.f, 0.f);
        int k = 0;
        for (; k + 4 <= n; k += 4) {
            int2 r0 = recs[start + k];
            int2 r1 = recs[start + k + 1];
            int2 r2 = recs[start + k + 2];
            int2 r3 = recs[start + k + 3];
            float4 g0 = bf4_to_f4(*(const ushort4*)(ebf + (size_t)r0.x * CHN + cg * 4));
            float4 g1 = bf4_to_f4(*(const ushort4*)(ebf + (size_t)r1.x * CHN + cg * 4));
            float4 g2 = bf4_to_f4(*(const ushort4*)(ebf + (size_t)r2.x * CHN + cg * 4));
            float4 g3 = bf4_to_f4(*(const ushort4*)(ebf + (size_t)r3.x * CHN + cg * 4));
            float4 w0 = *(const float4*)&wl[r0.y * CHN + cg * 4];
            float4 w1 = *(const float4*)&wl[r1.y * CHN + cg * 4];
            float4 w2 = *(const float4*)&wl[r2.y * CHN + cg * 4];
            float4 w3 = *(const float4*)&wl[r3.y * CHN + cg * 4];
            acc.x += g0.x * w0.x + g1.x * w1.x + g2.x * w2.x + g3.x * w3.x;
            acc.y += g0.y * w0.y + g1.y * w1.y + g2.y * w2.y + g3.y * w3.y;
            acc.z += g0.z * w0.z + g1.z * w1.z + g2.z * w2.z + g3.z * w3.z;
            acc.w += g0.w * w0.w + g1.w * w1.w + g2.w * w2.w + g3.w * w3.w;
        }
        for (; k < n; ++k) {
            int2 r0 = recs[start + k];
            float4 g0 = bf4_to_f4(*(const ushort4*)(ebf + (size_t)r0.x * CHN + cg * 4));
            float4 w0 = *(const float4*)&wl[r0.y * CHN + cg * 4];
            acc.x += g0.x * w0.x; acc.y += g0.y * w0.y;
            acc.z += g0.z * w0.z; acc.w += g0.w * w0.w;
        }
        float d = (n > 0) ? (float)n : 1.f;
        float inv_d = 1.f / d;
        float4 x = make_float4(acc.x * inv_d, acc.y * inv_d, acc.z * inv_d, acc.w * inv_d);
        float ss = x.x * x.x + x.y * x.y + x.z * x.z + x.w * x.w;
        #pragma unroll
        for (int off = 8; off > 0; off >>= 1) ss += __shfl_xor(ss, off, 64);
        float innv = 1.f / fmaxf(sqrtf(ss), 1e-12f);
        float4 y = make_float4(x.x * innv, x.y * innv, x.z * innv, x.w * innv);
        if (ebf_new)
            *(ushort4*)(ebf_new + (size_t)row * CHN + cg * 4) =
                make_ushort4(f2bf(y.x), f2bf(y.y), f2bf(y.z), f2bf(y.w));
        float4 r = *(const float4*)&ent_resid[(size_t)row * CHN + cg * 4];
        *(float4*)&out_ent[(size_t)row * CHN + cg * 4] =
            make_float4(r.x + y.x, r.y + y.y, r.z + y.z, r.w + y.w);
    } else {
        unsigned ur = row - N_ENTITIES;
        float4 uo = *(const float4*)&u_src[(size_t)ur * CHN + cg * 4];

        // score = softmax(u_old @ latent^T) over 4 factors
        float dot[N_FACTORS];
        #pragma unroll
        for (int f = 0; f < N_FACTORS; ++f) {
            float4 lf = *(const float4*)&latent[f * CHN + cg * 4];
            float p = uo.x * lf.x + uo.y * lf.y + uo.z * lf.z + uo.w * lf.w;
            #pragma unroll
            for (int off = 8; off > 0; off >>= 1) p += __shfl_xor(p, off, 64);
            dot[f] = p;
        }
        float m = fmaxf(fmaxf(dot[0], dot[1]), fmaxf(dot[2], dot[3]));
        float es = 0.f;
        #pragma unroll
        for (int f = 0; f < N_FACTORS; ++f) { dot[f] = expf(dot[f] - m); es += dot[f]; }
        float sinv = 1.f / es;
        float4 mix = make_float4(0.f, 0.f, 0.f, 0.f);
        #pragma unroll
        for (int f = 0; f < N_FACTORS; ++f) {
            float sc = dot[f] * sinv;
            float4 dw = *(const float4*)&disenw[f * CHN + cg * 4];
            mix.x += sc * dw.x; mix.y += sc * dw.y;
            mix.z += sc * dw.z; mix.w += sc * dw.w;
        }

        float4 acc = make_float4(0.f, 0.f, 0.f, 0.f);
        int k = 0;
        for (; k + 4 <= n; k += 4) {
            int2 r0 = recs[start + k];
            int2 r1 = recs[start + k + 1];
            int2 r2 = recs[start + k + 2];
            int2 r3 = recs[start + k + 3];
            float4 g0 = bf4_to_f4(*(const ushort4*)(ebf + (size_t)r0.x * CHN + cg * 4));
            float4 g1 = bf4_to_f4(*(const ushort4*)(ebf + (size_t)r1.x * CHN + cg * 4));
            float4 g2 = bf4_to_f4(*(const ushort4*)(ebf + (size_t)r2.x * CHN + cg * 4));
            float4 g3 = bf4_to_f4(*(const ushort4*)(ebf + (size_t)r3.x * CHN + cg * 4));
            float v0 = __int_as_float(r0.y), v1 = __int_as_float(r1.y);
            float v2 = __int_as_float(r2.y), v3 = __int_as_float(r3.y);
            acc.x += g0.x * v0 + g1.x * v1 + g2.x * v2 + g3.x * v3;
            acc.y += g0.y * v0 + g1.y * v1 + g2.y * v2 + g3.y * v3;
            acc.z += g0.z * v0 + g1.z * v1 + g2.z * v2 + g3.z * v3;
            acc.w += g0.w * v0 + g1.w * v1 + g2.w * v2 + g3.w * v3;
        }
        for (; k < n; ++k) {
            int2 r0 = recs[start + k];
            float4 g0 = bf4_to_f4(*(const ushort4*)(ebf + (size_t)r0.x * CHN + cg * 4));
            float v0 = __int_as_float(r0.y);
            acc.x += g0.x * v0; acc.y += g0.y * v0;
            acc.z += g0.z * v0; acc.w += g0.w * v0;
        }
        float4 x = make_float4(acc.x * (1.f + mix.x), acc.y * (1.f + mix.y),
                               acc.z * (1.f + mix.z), acc.w * (1.f + mix.w));
        float ss = x.x * x.x + x.y * x.y + x.z * x.z + x.w * x.w;
        #pragma unroll
        for (int off = 8; off > 0; off >>= 1) ss += __shfl_xor(ss, off, 64);
        float innv = 1.f / fmaxf(sqrtf(ss), 1e-12f);
        float4 y = make_float4(x.x * innv, x.y * innv, x.z * innv, x.w * innv);
        if (u_new)
            *(float4*)&u_new[(size_t)ur * CHN + cg * 4] = y;
        float4 r = *(const float4*)&usr_resid[(size_t)ur * CHN + cg * 4];
        *(float4*)&out_usr[(size_t)ur * CHN + cg * 4] =
            make_float4(r.x + y.x, r.y + y.y, r.z + y.z, r.w + y.w);
    }
}

extern "C" void kernel_launch(void* const* d_in, const int* in_sizes, int n_in,
                              void* d_out, int out_size, void* d_ws, size_t ws_size,
                              hipStream_t stream) {
    const float* user_emb   = (const float*)d_in[0];
    const float* entity_emb = (const float*)d_in[1];
    const float* latent_emb = (const float*)d_in[2];
    const float* weight     = (const float*)d_in[3];
    const float* att        = (const float*)d_in[4];
    const float* inter_val  = (const float*)d_in[5];
    const int*   edge_index = (const int*)d_in[6];   // [2][N_EDGES]
    const int*   edge_type  = (const int*)d_in[7];
    const int*   inter_row  = (const int*)d_in[8];
    const int*   inter_col  = (const int*)d_in[9];

    const int* head = edge_index;
    const int* tail = edge_index + N_EDGES;

    float* out_ent = (float*)d_out;                              // [250000*64]
    float* out_usr = out_ent + (size_t)N_ENTITIES * CHN;         // [150000*64]
    float* out_cor = out_usr + (size_t)N_USERS * CHN;            // [1]

    // workspace layout
    unsigned short* ebf0  = (unsigned short*)d_ws;               // 16M bf16 (input entities)
    unsigned short* ebfA  = ebf0 + (size_t)N_ENTITIES * CHN;     // 16M bf16 (hop-1 entities)
    float* u      = (float*)(ebfA + (size_t)N_ENTITIES * CHN);   //  9,600,000 f
    float* disenw = u + (size_t)N_USERS * CHN;                   //        256 f
    int*   recs   = (int*)(disenw + 256);                        //  4,000,000 i (int2 x 2M)
    int*   cnt    = recs + 2 * NRECS;                            //    400,000 i
    int*   offs   = cnt + NROWS;                                 //    400,000 i
    int*   cur    = offs + NROWS;                                //    400,000 i
    int*   bs     = cur + NROWS;                                 //      1,024 i

    const int rec_blocks  = (NRECS + 255) / 256;                 // 7813
    const int scan_blocks = (NROWS + SCHUNK - 1) / SCHUNK;       // 782

    // ---- build unified CSR (entities rows [0,250k), users rows [250k,400k)) ----
    hipMemsetAsync(cnt, 0, (size_t)NROWS * sizeof(int), stream);
    count_all_kernel<<<rec_blocks, 256, 0, stream>>>(head, inter_row, cnt);
    block_sum_kernel<<<scan_blocks, SCHUNK, 0, stream>>>(cnt, bs, NROWS);
    scan_small_kernel<<<1, 1024, 0, stream>>>(bs, scan_blocks);
    scan_chunk_kernel<<<scan_blocks, SCHUNK, 0, stream>>>(cnt, bs, offs, cur, NROWS);
    scatter_all_kernel<<<rec_blocks, 256, 0, stream>>>(head, tail, edge_type,
                                                       inter_row, inter_col, inter_val,
                                                       cur, (int2*)recs);

    prep_small_kernel<<<1, 256, 0, stream>>>(weight, att, disenw, out_cor);

    // bf16 copy of input entity table
    {
        int n4 = N_ENTITIES * CHN / 4;                           // 4,000,000
        conv_bf16_kernel<<<(n4 + 255) / 256, 256, 0, stream>>>(
            (const float4*)entity_emb, (ushort4*)ebf0, n4);
    }

    const int hop_blocks = (NROWS * 16 + 255) / 256;             // 25000

    // ---- hop 1: gather from ebf0; residual base = inputs; emit ebfA + u ----
    hop_kernel<<<hop_blocks, 256, 0, stream>>>(ebf0, user_emb, (const int2*)recs,
                                               cnt, offs, weight, latent_emb, disenw,
                                               entity_emb, user_emb,
                                               ebfA, u, out_ent, out_usr);

    // ---- hop 2: gather from ebfA; residual base = out (in-place add) ----
    hop_kernel<<<hop_blocks, 256, 0, stream>>>(ebfA, u, (const int2*)recs,
                                               cnt, offs, weight, latent_emb, disenw,
                                               out_ent, out_usr,
                                               nullptr, nullptr, out_ent, out_usr);
}